// Round 1
// baseline (634.005 us; speedup 1.0000x reference)
//
#include <hip/hip_runtime.h>
#include <math.h>

namespace {
constexpr int Cn = 256;
constexpr int Kn = 19;
constexpr int HW = 256 * 256;          // 65536
constexpr int P  = 4 * HW;             // 262144 pixels
constexpr float TAUv = 0.07f;
constexpr float EPSv = 1e-12f;

// workspace layout (floats)
constexpr int K0_OFF   = 0;            // [19][256] prototype accumulators
constexpr int K0N_OFF  = 4864;         // [19][256] normalized prototypes
constexpr int SUMS_OFF = 9728;         // {loss_sum, num_pos}
constexpr int ZERO_N   = 9730;
constexpr int P1_GRID  = 1024;
constexpr int P3_GRID  = P / 256;      // 1024
}

// Wave-uniform broadcast: lift an LDS-loaded (uniform) value into an SGPR so
// downstream selects become s_cselect and FMAs take a scalar operand.
__device__ __forceinline__ float bcast_f(float x) {
  return __uint_as_float((unsigned)__builtin_amdgcn_readfirstlane((int)__float_as_uint(x)));
}
__device__ __forceinline__ unsigned bcast_u(unsigned x) {
  return (unsigned)__builtin_amdgcn_readfirstlane((int)x);
}

__global__ __launch_bounds__(256) void gc_init(float* __restrict__ ws) {
  int i = blockIdx.x * 256 + threadIdx.x;
  if (i < ZERO_N) ws[i] = 0.0f;
}

// Phase 1: k0[k][c] = sum over pixels of pos[k,p] * fnorm[c,p]
// 32px x 256c tile (32 KB -> 4 blocks/CU). Thread t accumulates channel c=t.
// Per-pixel weight is (rn, mask) broadcast to SGPRs -> inner loop is
// s_cselect + v_fmac (scalar pipe + VALU), no b128 LDS broadcasts.
__global__ __launch_bounds__(256, 4) void gc_phase1(const float* __restrict__ feat,
                                                    const float* __restrict__ gt,
                                                    float* __restrict__ k0) {
  __shared__ float tile[32 * 256];   // [p][c ^ p], 32 KB
  __shared__ float part[256];        // sumsq partials
  __shared__ float rnL[32];          // per-pixel 1/||f||
  __shared__ unsigned mskL[32];      // per-pixel 19-bit positive mask

  const int t = threadIdx.x;
  const int p = t & 31;              // pixel this thread stages
  const int g = t >> 5;              // channel group (8 groups of 32)

  float acc[Kn];
#pragma unroll
  for (int k = 0; k < Kn; k++) acc[k] = 0.0f;

  for (int tid = blockIdx.x; tid < P / 32; tid += gridDim.x) {
    const int p0  = tid << 5;
    const int b   = p0 >> 16;              // HW == 65536
    const int hw0 = p0 & (HW - 1);
    const float* fb = feat + (size_t)b * (Cn * HW) + hw0;

    __syncthreads();   // previous tile fully consumed

    // stage: thread t loads pixel p, channels g*32+j (32 loads in flight)
    float v[32];
#pragma unroll
    for (int j = 0; j < 32; j++) v[j] = fb[(size_t)((g << 5) + j) * HW + p];
    float ss = 0.0f;
#pragma unroll
    for (int j = 0; j < 32; j++) {
      const int c = (g << 5) + j;
      ss += v[j] * v[j];
      tile[(p << 8) + (c ^ p)] = v[j];
    }
    part[t] = ss;

    unsigned msk = 0;
    if (t < 32) {   // t == p here; gt fetched once per pixel
      const float* gb = gt + (size_t)b * (Kn * HW) + hw0 + p;
#pragma unroll
      for (int k = 0; k < Kn; k++)
        msk |= (gb[(size_t)k * HW] == 1.0f) ? (1u << k) : 0u;
    }

    __syncthreads();   // tile + partials visible

    if (t < 32) {
      float fss = 0.0f;
#pragma unroll
      for (int q = 0; q < 8; q++) fss += part[(q << 5) + p];
      rnL[p]  = 1.0f / fmaxf(sqrtf(fss), EPSv);
      mskL[p] = msk;
    }

    __syncthreads();   // rnL/mskL visible

    // accumulate: thread t owns channel c=t, loops over the 32 pixels.
    // rn/mk are wave-uniform scalars: w = bit ? rn : 0 is an s_cselect,
    // acc update is v_fmac_f32 v, s, v. Same arithmetic as before
    // (fmaf(fv, rn-or-0, acc)), so bitwise-identical results.
#pragma unroll 8
    for (int pp = 0; pp < 32; pp++) {
      const float    rn = bcast_f(rnL[pp]);
      const unsigned mk = bcast_u(mskL[pp]);
      const float    fv = tile[(pp << 8) + (t ^ pp)];
#pragma unroll
      for (int k = 0; k < Kn; k++) {
        const float w = ((mk >> k) & 1u) ? rn : 0.0f;
        acc[k] = fmaf(fv, w, acc[k]);
      }
    }
  }

#pragma unroll
  for (int k = 0; k < Kn; k++) atomicAdd(&k0[k * 256 + t], acc[k]);
}

// Phase 2: row-normalize k0 -> k0n
__global__ __launch_bounds__(256) void gc_phase2(const float* __restrict__ k0,
                                                 float* __restrict__ k0n) {
  const int lane = threadIdx.x & 63;
  const int wv   = threadIdx.x >> 6;
  for (int r = wv; r < Kn; r += 4) {
    float s = 0.0f;
#pragma unroll
    for (int j = 0; j < 4; j++) {
      const float v = k0[r * 256 + (j << 6) + lane];
      s += v * v;
    }
#pragma unroll
    for (int off = 32; off > 0; off >>= 1) s += __shfl_down(s, off);
    s = __shfl(s, 0);
    const float rn = 1.0f / fmaxf(sqrtf(s), EPSv);
#pragma unroll
    for (int j = 0; j < 4; j++) {
      const int c = (j << 6) + lane;
      k0n[r * 256 + c] = k0[r * 256 + c] * rn;
    }
  }
}

// Phase 3 helpers: feat channels live in registers (no LDS round-trip);
// k0n reads are wave-uniform -> s_load_dwordx4 on the scalar pipe.
__device__ __forceinline__ void p3_load(float (&dst)[16],
                                        const float* __restrict__ fb, int base) {
#pragma unroll
  for (int j = 0; j < 16; j++) dst[j] = fb[(size_t)(base + j) * HW];
}

__device__ __forceinline__ void p3_compute(const float (&v)[16], int c0,
                                           const float* __restrict__ k0n,
                                           float (&dot)[Kn], float& ss) {
#pragma unroll
  for (int j4 = 0; j4 < 16; j4 += 4) {
    const float f0 = v[j4 + 0], f1 = v[j4 + 1];
    const float f2 = v[j4 + 2], f3 = v[j4 + 3];
    ss = fmaf(f0, f0, ss); ss = fmaf(f1, f1, ss);
    ss = fmaf(f2, f2, ss); ss = fmaf(f3, f3, ss);
#pragma unroll
    for (int k = 0; k < Kn; k++) {
      const float4 w = *(const float4*)(k0n + k * 256 + c0 + j4);  // uniform
      dot[k] = fmaf(f3, w.w, fmaf(f2, w.z, fmaf(f1, w.y, fmaf(f0, w.x, dot[k]))));
    }
  }
}

// Phase 3: logits + log-softmax + masked loss. Thread t owns pixel
// blockIdx*256+t; channels double-buffered in registers (va/vb), weights
// come in as scalar loads -> no LDS, no __syncthreads.
__global__ __launch_bounds__(256, 4) void gc_phase3(const float* __restrict__ feat,
                                                    const float* __restrict__ gt,
                                                    const float* __restrict__ k0n,
                                                    float* __restrict__ sums) {
  const int t    = threadIdx.x;
  const int pix0 = blockIdx.x << 8;
  const int b    = pix0 >> 16;
  const int hw   = (pix0 & (HW - 1)) + t;
  const float* fb = feat + (size_t)b * (Cn * HW) + hw;

  float dot[Kn];
#pragma unroll
  for (int k = 0; k < Kn; k++) dot[k] = 0.0f;
  float ss = 0.0f;

  float va[16], vb[16];
  p3_load(va, fb, 0);
  for (int c0 = 0; c0 < Cn; c0 += 32) {
    p3_load(vb, fb, c0 + 16);            // prefetch odd chunk
    p3_compute(va, c0, k0n, dot, ss);    // consume even chunk
    if (c0 + 32 < Cn) p3_load(va, fb, c0 + 32);  // prefetch next even chunk
    p3_compute(vb, c0 + 16, k0n, dot, ss);       // consume odd chunk
  }

  const float sc = 1.0f / (fmaxf(sqrtf(ss), EPSv) * TAUv);
  float mx = -1e30f;
#pragma unroll
  for (int k = 0; k < Kn; k++) { dot[k] *= sc; mx = fmaxf(mx, dot[k]); }
  float se = 0.0f;
#pragma unroll
  for (int k = 0; k < Kn; k++) se += __expf(dot[k] - mx);
  const float lse = __logf(se) + mx;

  const float* gb = gt + (size_t)b * (Kn * HW) + hw;
  float lsum = 0.0f, npos = 0.0f;
#pragma unroll
  for (int k = 0; k < Kn; k++) {
    if (gb[(size_t)k * HW] == 1.0f) { lsum += lse - dot[k]; npos += 1.0f; }
  }

#pragma unroll
  for (int off = 32; off > 0; off >>= 1) {
    lsum += __shfl_down(lsum, off);
    npos += __shfl_down(npos, off);
  }
  if ((t & 63) == 0) {
    atomicAdd(&sums[0], lsum);
    atomicAdd(&sums[1], npos);
  }
}

__global__ void gc_finalize(const float* __restrict__ sums, float* __restrict__ out) {
  if (threadIdx.x == 0 && blockIdx.x == 0)
    out[0] = sums[0] / sums[1];
}

extern "C" void kernel_launch(void* const* d_in, const int* in_sizes, int n_in,
                              void* d_out, int out_size, void* d_ws, size_t ws_size,
                              hipStream_t stream) {
  const float* feat = (const float*)d_in[0];
  const float* gt   = (const float*)d_in[1];
  float* ws  = (float*)d_ws;
  float* out = (float*)d_out;

  float* k0   = ws + K0_OFF;
  float* k0n  = ws + K0N_OFF;
  float* sums = ws + SUMS_OFF;

  gc_init<<<dim3((ZERO_N + 255) / 256), dim3(256), 0, stream>>>(ws);
  gc_phase1<<<dim3(P1_GRID), dim3(256), 0, stream>>>(feat, gt, k0);
  gc_phase2<<<dim3(1), dim3(256), 0, stream>>>(k0, k0n);
  gc_phase3<<<dim3(P3_GRID), dim3(256), 0, stream>>>(feat, gt, k0n, sums);
  gc_finalize<<<dim3(1), dim3(64), 0, stream>>>(sums, out);
}

// Round 3
// 549.405 us; speedup vs baseline: 1.1540x; 1.1540x over previous
//
#include <hip/hip_runtime.h>
#include <math.h>

namespace {
constexpr int Cn = 256;
constexpr int Kn = 19;
constexpr int HW = 256 * 256;          // 65536
constexpr int P  = 4 * HW;             // 262144 pixels
constexpr float TAUv = 0.07f;
constexpr float EPSv = 1e-12f;

// workspace layout (floats)
constexpr int K0_OFF   = 0;            // [19][256] prototype accumulators
constexpr int K0N_OFF  = 4864;         // [19][256] normalized prototypes
constexpr int SUMS_OFF = 9728;         // {loss_sum, num_pos}
constexpr int ZERO_N   = 9730;
constexpr int P1_GRID  = 1024;
constexpr int P3_GRID  = P / 512;      // 512 blocks, 4 px/thread, 128 thr
}

// Wave-uniform broadcast -> SGPR (selects become s_cselect, FMA takes scalar).
__device__ __forceinline__ float bcast_f(float x) {
  return __uint_as_float((unsigned)__builtin_amdgcn_readfirstlane((int)__float_as_uint(x)));
}
__device__ __forceinline__ unsigned bcast_u(unsigned x) {
  return (unsigned)__builtin_amdgcn_readfirstlane((int)x);
}

__global__ __launch_bounds__(256) void gc_init(float* __restrict__ ws) {
  int i = blockIdx.x * 256 + threadIdx.x;
  if (i < ZERO_N) ws[i] = 0.0f;
}

// Phase 1: k0[k][c] = sum over pixels of pos[k,p] * fnorm[c,p]
// 32px x 256c tile. Staging now float4 (4px x 8ch per thread, 16B/lane) to
// break the ~1.45 TB/s dword-issue bandwidth cap seen in rounds 0-1.
__global__ __launch_bounds__(256, 4) void gc_phase1(const float* __restrict__ feat,
                                                    const float* __restrict__ gt,
                                                    float* __restrict__ k0) {
  __shared__ float tile[32 * 256];   // [p][c ^ p], 32 KB (XOR keeps writes 2-way)
  __shared__ float part2[32][33];    // [p][g] sumsq partials, padded (2-way max)
  __shared__ float rnL[32];          // per-pixel 1/||f||
  __shared__ unsigned mskL[32];      // per-pixel 19-bit positive mask

  const int t  = threadIdx.x;
  const int pq = t & 7;              // pixel quad (4 consecutive px)
  const int g  = t >> 3;             // 8-channel group (32 groups)

  float acc[Kn];
#pragma unroll
  for (int k = 0; k < Kn; k++) acc[k] = 0.0f;

  for (int tid = blockIdx.x; tid < P / 32; tid += gridDim.x) {
    const int p0  = tid << 5;
    const int b   = p0 >> 16;              // HW == 65536
    const int hw0 = p0 & (HW - 1);
    const float* fb = feat + (size_t)b * (Cn * HW) + hw0;

    __syncthreads();   // previous tile fully consumed

    // stage: thread t loads pixels pq*4..pq*4+3, channels g*8..g*8+7
    // as 8 float4 (16B/lane, 8 loads in flight)
    float4 v4[8];
#pragma unroll
    for (int j = 0; j < 8; j++)
      v4[j] = *(const float4*)&fb[(size_t)((g << 3) + j) * HW + (pq << 2)];

    float ps0 = 0.f, ps1 = 0.f, ps2 = 0.f, ps3 = 0.f;
#pragma unroll
    for (int j = 0; j < 8; j++) {
      const int c  = (g << 3) + j;
      const int px = pq << 2;
      ps0 = fmaf(v4[j].x, v4[j].x, ps0);
      ps1 = fmaf(v4[j].y, v4[j].y, ps1);
      ps2 = fmaf(v4[j].z, v4[j].z, ps2);
      ps3 = fmaf(v4[j].w, v4[j].w, ps3);
      tile[((px + 0) << 8) + (c ^ (px + 0))] = v4[j].x;
      tile[((px + 1) << 8) + (c ^ (px + 1))] = v4[j].y;
      tile[((px + 2) << 8) + (c ^ (px + 2))] = v4[j].z;
      tile[((px + 3) << 8) + (c ^ (px + 3))] = v4[j].w;
    }
    part2[(pq << 2) + 0][g] = ps0;
    part2[(pq << 2) + 1][g] = ps1;
    part2[(pq << 2) + 2][g] = ps2;
    part2[(pq << 2) + 3][g] = ps3;

    unsigned msk = 0;
    if (t < 32) {   // gt fetched once per pixel (p == t)
      const float* gb = gt + (size_t)b * (Kn * HW) + hw0 + t;
#pragma unroll
      for (int k = 0; k < Kn; k++)
        msk |= (gb[(size_t)k * HW] == 1.0f) ? (1u << k) : 0u;
    }

    __syncthreads();   // tile + partials visible

    if (t < 32) {
      float fss = 0.0f;
#pragma unroll
      for (int gg = 0; gg < 32; gg++) fss += part2[t][gg];
      rnL[t]  = 1.0f / fmaxf(sqrtf(fss), EPSv);
      mskL[t] = msk;
    }

    __syncthreads();   // rnL/mskL visible

    // accumulate: thread t owns channel c=t, loops over the 32 pixels.
    // rn/mk are wave-uniform scalars -> s_cselect + v_fmac.
#pragma unroll 8
    for (int pp = 0; pp < 32; pp++) {
      const float    rn = bcast_f(rnL[pp]);
      const unsigned mk = bcast_u(mskL[pp]);
      const float    fv = tile[(pp << 8) + (t ^ pp)];
#pragma unroll
      for (int k = 0; k < Kn; k++) {
        const float w = ((mk >> k) & 1u) ? rn : 0.0f;
        acc[k] = fmaf(fv, w, acc[k]);
      }
    }
  }

#pragma unroll
  for (int k = 0; k < Kn; k++) atomicAdd(&k0[k * 256 + t], acc[k]);
}

// Phase 2: row-normalize k0 -> k0n
__global__ __launch_bounds__(256) void gc_phase2(const float* __restrict__ k0,
                                                 float* __restrict__ k0n) {
  const int lane = threadIdx.x & 63;
  const int wv   = threadIdx.x >> 6;
  for (int r = wv; r < Kn; r += 4) {
    float s = 0.0f;
#pragma unroll
    for (int j = 0; j < 4; j++) {
      const float v = k0[r * 256 + (j << 6) + lane];
      s += v * v;
    }
#pragma unroll
    for (int off = 32; off > 0; off >>= 1) s += __shfl_down(s, off);
    s = __shfl(s, 0);
    const float rn = 1.0f / fmaxf(sqrtf(s), EPSv);
#pragma unroll
    for (int j = 0; j < 4; j++) {
      const int c = (j << 6) + lane;
      k0n[r * 256 + c] = k0[r * 256 + c] * rn;
    }
  }
}

// Phase 3 helpers: 4 pixels/thread, float4 loads (16B/lane), weights on the
// scalar pipe (wave-uniform k0n reads -> s_load_dwordx4).
__device__ __forceinline__ void p3_load4(float4 (&dst)[8],
                                         const float* __restrict__ fb, int base) {
#pragma unroll
  for (int j = 0; j < 8; j++)
    dst[j] = *(const float4*)&fb[(size_t)(base + j) * HW];
}

__device__ __forceinline__ void p3_compute4(const float4 (&v)[8], int c0,
                                            const float* __restrict__ k0n,
                                            float (&dot)[Kn][4], float (&ss)[4]) {
#pragma unroll
  for (int j4 = 0; j4 < 8; j4 += 4) {
    const float4 f0 = v[j4 + 0], f1 = v[j4 + 1];
    const float4 f2 = v[j4 + 2], f3 = v[j4 + 3];
    ss[0] = fmaf(f0.x, f0.x, ss[0]); ss[0] = fmaf(f1.x, f1.x, ss[0]);
    ss[0] = fmaf(f2.x, f2.x, ss[0]); ss[0] = fmaf(f3.x, f3.x, ss[0]);
    ss[1] = fmaf(f0.y, f0.y, ss[1]); ss[1] = fmaf(f1.y, f1.y, ss[1]);
    ss[1] = fmaf(f2.y, f2.y, ss[1]); ss[1] = fmaf(f3.y, f3.y, ss[1]);
    ss[2] = fmaf(f0.z, f0.z, ss[2]); ss[2] = fmaf(f1.z, f1.z, ss[2]);
    ss[2] = fmaf(f2.z, f2.z, ss[2]); ss[2] = fmaf(f3.z, f3.z, ss[2]);
    ss[3] = fmaf(f0.w, f0.w, ss[3]); ss[3] = fmaf(f1.w, f1.w, ss[3]);
    ss[3] = fmaf(f2.w, f2.w, ss[3]); ss[3] = fmaf(f3.w, f3.w, ss[3]);
#pragma unroll
    for (int k = 0; k < Kn; k++) {
      const float4 w = *(const float4*)(k0n + k * 256 + c0 + j4);  // uniform
      dot[k][0] = fmaf(f3.x, w.w, fmaf(f2.x, w.z, fmaf(f1.x, w.y, fmaf(f0.x, w.x, dot[k][0]))));
      dot[k][1] = fmaf(f3.y, w.w, fmaf(f2.y, w.z, fmaf(f1.y, w.y, fmaf(f0.y, w.x, dot[k][1]))));
      dot[k][2] = fmaf(f3.z, w.w, fmaf(f2.z, w.z, fmaf(f1.z, w.y, fmaf(f0.z, w.x, dot[k][2]))));
      dot[k][3] = fmaf(f3.w, w.w, fmaf(f2.w, w.z, fmaf(f1.w, w.y, fmaf(f0.w, w.x, dot[k][3]))));
    }
  }
}

// Phase 3: logits + log-softmax + masked loss. 512 blocks x 128 threads,
// thread owns 4 consecutive pixels; all global reads are dwordx4.
__global__ __launch_bounds__(128, 2) void gc_phase3(const float* __restrict__ feat,
                                                    const float* __restrict__ gt,
                                                    const float* __restrict__ k0n,
                                                    float* __restrict__ sums) {
  const int t    = threadIdx.x;
  const int pix0 = blockIdx.x << 9;          // 512 px per block
  const int b    = pix0 >> 16;
  const int hw   = (pix0 & (HW - 1)) + (t << 2);
  const float* fb = feat + (size_t)b * (Cn * HW) + hw;

  float dot[Kn][4];
#pragma unroll
  for (int k = 0; k < Kn; k++)
#pragma unroll
    for (int i = 0; i < 4; i++) dot[k][i] = 0.0f;
  float ss[4] = {0.f, 0.f, 0.f, 0.f};

  float4 va[8], vb[8];
  p3_load4(va, fb, 0);
  for (int c0 = 0; c0 < Cn; c0 += 16) {
    p3_load4(vb, fb, c0 + 8);                  // prefetch odd chunk
    p3_compute4(va, c0, k0n, dot, ss);         // consume even chunk
    if (c0 + 16 < Cn) p3_load4(va, fb, c0 + 16);
    p3_compute4(vb, c0 + 8, k0n, dot, ss);     // consume odd chunk
  }

  const float* gb = gt + (size_t)b * (Kn * HW) + hw;
  float4 gv[Kn];
#pragma unroll
  for (int k = 0; k < Kn; k++) gv[k] = *(const float4*)&gb[(size_t)k * HW];

  float lsum = 0.0f, npos = 0.0f;
#pragma unroll
  for (int i = 0; i < 4; i++) {
    const float sc = 1.0f / (fmaxf(sqrtf(ss[i]), EPSv) * TAUv);
    float mx = -1e30f;
    float d[Kn];
#pragma unroll
    for (int k = 0; k < Kn; k++) { d[k] = dot[k][i] * sc; mx = fmaxf(mx, d[k]); }
    float se = 0.0f;
#pragma unroll
    for (int k = 0; k < Kn; k++) se += __expf(d[k] - mx);
    const float lse = __logf(se) + mx;
#pragma unroll
    for (int k = 0; k < Kn; k++) {
      const float gvi = (i == 0) ? gv[k].x : (i == 1) ? gv[k].y : (i == 2) ? gv[k].z : gv[k].w;
      if (gvi == 1.0f) { lsum += lse - d[k]; npos += 1.0f; }
    }
  }

#pragma unroll
  for (int off = 32; off > 0; off >>= 1) {
    lsum += __shfl_down(lsum, off);
    npos += __shfl_down(npos, off);
  }
  if ((t & 63) == 0) {
    atomicAdd(&sums[0], lsum);
    atomicAdd(&sums[1], npos);
  }
}

__global__ void gc_finalize(const float* __restrict__ sums, float* __restrict__ out) {
  if (threadIdx.x == 0 && blockIdx.x == 0)
    out[0] = sums[0] / sums[1];
}

extern "C" void kernel_launch(void* const* d_in, const int* in_sizes, int n_in,
                              void* d_out, int out_size, void* d_ws, size_t ws_size,
                              hipStream_t stream) {
  const float* feat = (const float*)d_in[0];
  const float* gt   = (const float*)d_in[1];
  float* ws  = (float*)d_ws;
  float* out = (float*)d_out;

  float* k0   = ws + K0_OFF;
  float* k0n  = ws + K0N_OFF;
  float* sums = ws + SUMS_OFF;

  gc_init<<<dim3((ZERO_N + 255) / 256), dim3(256), 0, stream>>>(ws);
  gc_phase1<<<dim3(P1_GRID), dim3(256), 0, stream>>>(feat, gt, k0);
  gc_phase2<<<dim3(1), dim3(256), 0, stream>>>(k0, k0n);
  gc_phase3<<<dim3(P3_GRID), dim3(128), 0, stream>>>(feat, gt, k0n, sums);
  gc_finalize<<<dim3(1), dim3(64), 0, stream>>>(sums, out);
}